// Round 19
// baseline (316.277 us; speedup 1.0000x reference)
//
#include <hip/hip_runtime.h>
#include <math.h>

#define N_NODES  50000
#define N_EDGES  800000
#define FDIM     128
#define N_GRAPHS 500
#define NEG_SLOPE 0.2f
#define EN_TOTAL (N_EDGES + N_NODES)
#define GEMM_TILES (N_NODES / 16)         // 3125 exact
#define WT_COLS 144                        // 128 + [wa_src, wa_dst, 14 zero]
#define PREP_PLANE_BLOCKS 1024
#define BSHIFT 8
#define BWIDTH 256
#define NBUCK ((N_NODES + BWIDTH - 1) / BWIDTH)   // 196
#define BIN_BATCH 8192
#define BIN_BLOCKS ((EN_TOTAL + BIN_BATCH - 1) / BIN_BATCH)  // 104
#define PREP_GRID (3 + PREP_PLANE_BLOCKS + BIN_BLOCKS)

typedef short bf16x8 __attribute__((ext_vector_type(8)));
typedef float f32x4 __attribute__((ext_vector_type(4)));
typedef const __attribute__((address_space(1))) void* gas_ptr;
typedef __attribute__((address_space(3))) void* las_ptr;

static __device__ __forceinline__ float lrelu(float x) {
    return x >= 0.f ? x : NEG_SLOPE * x;
}
static __device__ __forceinline__ unsigned short f2bf(float v) {
    unsigned int u = __float_as_uint(v);
    u += 0x7fffu + ((u >> 16) & 1u);
    return (unsigned short)(u >> 16);
}
static __device__ __forceinline__ float bf2f(unsigned short s) {
    return __uint_as_float(((unsigned int)s) << 16);
}

// ---- fused prep: blocks 0-2 build WT (hi/lo); blocks 3..1026 bf16-split X
//      (single plane); blocks 1027..1130 write per-block bucket histograms.
__global__ __launch_bounds__(256) void prep_all(
    const float* __restrict__ X, const int* __restrict__ ei,
    const float* __restrict__ W0, const float* __restrict__ W1,
    const float* __restrict__ W2,
    const float* __restrict__ as0, const float* __restrict__ as1,
    const float* __restrict__ as2,
    const float* __restrict__ ad0, const float* __restrict__ ad1,
    const float* __restrict__ ad2,
    unsigned short* __restrict__ WT,
    unsigned short* __restrict__ PHI,
    int* __restrict__ bcnt_part)
{
    __shared__ float wa[256];
    __shared__ int hist[BWIDTH];
    const int b = blockIdx.x, tid = threadIdx.x;

    if (b < 3) {
        const float* W  = (b == 0) ? W0  : (b == 1) ? W1  : W2;
        const float* As = (b == 0) ? as0 : (b == 1) ? as1 : as2;
        const float* Ad = (b == 0) ? ad0 : (b == 1) ? ad1 : ad2;
        unsigned short* hi = WT + (size_t)b * 2 * WT_COLS * FDIM;
        unsigned short* lo = hi + WT_COLS * FDIM;
        {
            const int k = tid & 127;
            const float* av = (tid < 128) ? As : Ad;
            float s = 0.f;
            for (int c = 0; c < 128; ++c) s += W[k * FDIM + c] * av[c];
            wa[tid] = s;
        }
        __syncthreads();
        for (int i = tid; i < FDIM * FDIM; i += 256) {
            const int k = i >> 7, c = i & 127;
            const float v = W[i];
            const unsigned short h = f2bf(v);
            hi[c * FDIM + k] = h;
            lo[c * FDIM + k] = f2bf(v - bf2f(h));
        }
        for (int k = tid; k < FDIM; k += 256) {
            const float vs = wa[k], vd = wa[128 + k];
            const unsigned short hs = f2bf(vs), hd = f2bf(vd);
            hi[128 * FDIM + k] = hs; lo[128 * FDIM + k] = f2bf(vs - bf2f(hs));
            hi[129 * FDIM + k] = hd; lo[129 * FDIM + k] = f2bf(vd - bf2f(hd));
        }
        for (int i = tid; i < 14 * FDIM; i += 256) {
            hi[130 * FDIM + i] = 0;
            lo[130 * FDIM + i] = 0;
        }
    } else if (b < 3 + PREP_PLANE_BLOCKS) {
        const int total = N_NODES * FDIM / 4;
        for (int i = (b - 3) * 256 + tid; i < total; i += PREP_PLANE_BLOCKS * 256) {
            const float4 v = ((const float4*)X)[i];
            ushort4 h4;
            h4.x = f2bf(v.x);
            h4.y = f2bf(v.y);
            h4.z = f2bf(v.z);
            h4.w = f2bf(v.w);
            ((ushort4*)PHI)[i] = h4;
        }
    } else {
        const int cb = b - 3 - PREP_PLANE_BLOCKS;       // 0..BIN_BLOCKS-1
        if (tid < BWIDTH) hist[tid] = 0;
        __syncthreads();
        const int i0 = cb * BIN_BATCH;
        const int i1 = min(i0 + BIN_BATCH, EN_TOTAL);
        for (int i = i0 + tid; i < i1; i += 256) {
            const int d = (i < N_EDGES) ? ei[N_EDGES + i] : (i - N_EDGES);
            atomicAdd(&hist[d >> BSHIFT], 1);
        }
        __syncthreads();
        if (tid < BWIDTH) bcnt_part[cb * BWIDTH + tid] = hist[tid];
    }
}

// ---------------- h = X @ W: single-plane bf16 A, W hi/lo (2-pass) ------------
// A bf16 (2^-9 rel error, same class as the Hb rounding already in the
// pipeline); W stays fp32-accurate via hi/lo B planes. 16 MFMA/tile.
// Staging via global_load_lds w=16, XOR swizzle on the GLOBAL source.
__global__ __launch_bounds__(256) void gemm_mfma10(
    const unsigned short* __restrict__ PHI,
    const unsigned short* __restrict__ WThi, const unsigned short* __restrict__ WTlo,
    unsigned short* __restrict__ Hb, float* __restrict__ asrcN, float* __restrict__ adstN)
{
    __shared__ unsigned short sH[2][16 * 128];

    const int tid = threadIdx.x, wv = tid >> 6, lane = tid & 63;
    const int r16 = lane & 15, g = lane >> 4;
    const int t0 = wv * 2;

    bf16x8 bh[2][4], bl[2][4];
    #pragma unroll
    for (int tt = 0; tt < 2; ++tt) {
        const int c = (t0 + tt) * 16 + r16;
        #pragma unroll
        for (int cc = 0; cc < 4; ++cc) {
            bh[tt][cc] = *(const bf16x8*)(WThi + c * FDIM + cc * 32 + 8 * g);
            bl[tt][cc] = *(const bf16x8*)(WTlo + c * FDIM + cc * 32 + 8 * g);
        }
    }
    const unsigned short* WThiE = WThi + (128 + r16) * FDIM + 8 * g;
    const unsigned short* WTloE = WTlo + (128 + r16) * FDIM + 8 * g;

    const int srow = wv * 4 + (lane >> 4);
    const int gslot = (lane & 15) ^ (srow & 7);              // XOR involution
    const size_t gOfs0 = (size_t)srow * FDIM + gslot * 8;

    int tile = blockIdx.x;
    {
        const size_t go = (size_t)tile * 16 * FDIM + gOfs0;
        __builtin_amdgcn_global_load_lds((gas_ptr)(PHI + go), (las_ptr)&sH[0][wv * 512], 16, 0, 0);
    }
    __syncthreads();

    int cur = 0, rot = 0;
    for (; tile < GEMM_TILES; tile += gridDim.x, ++rot) {
        const int nxt = tile + (int)gridDim.x;
        if (nxt < GEMM_TILES) {
            const size_t go = (size_t)nxt * 16 * FDIM + gOfs0;
            __builtin_amdgcn_global_load_lds((gas_ptr)(PHI + go),
                                             (las_ptr)&sH[cur ^ 1][wv * 512], 16, 0, 0);
        }

        bf16x8 ah[4];
        #pragma unroll
        for (int cc = 0; cc < 4; ++cc) {
            const int p = (cc * 4 + g) ^ (r16 & 7);
            ah[cc] = *(const bf16x8*)(&sH[cur][r16 * 128 + p * 8]);
        }

        f32x4 acc0 = {0.f, 0.f, 0.f, 0.f}, acc1 = {0.f, 0.f, 0.f, 0.f};
        #pragma unroll
        for (int cc = 0; cc < 4; ++cc) {
            acc0 = __builtin_amdgcn_mfma_f32_16x16x32_bf16(ah[cc], bh[0][cc], acc0, 0, 0, 0);
            acc1 = __builtin_amdgcn_mfma_f32_16x16x32_bf16(ah[cc], bh[1][cc], acc1, 0, 0, 0);
            acc0 = __builtin_amdgcn_mfma_f32_16x16x32_bf16(ah[cc], bl[0][cc], acc0, 0, 0, 0);
            acc1 = __builtin_amdgcn_mfma_f32_16x16x32_bf16(ah[cc], bl[1][cc], acc1, 0, 0, 0);
        }

        const int m0 = tile * 16;
        const int rowb = m0 + 4 * g;
        #pragma unroll
        for (int r = 0; r < 4; ++r) {
            Hb[(size_t)(rowb + r) * FDIM + (t0 + 0) * 16 + r16] = f2bf(acc0[r]);
            Hb[(size_t)(rowb + r) * FDIM + (t0 + 1) * 16 + r16] = f2bf(acc1[r]);
        }

        if (wv == ((tile + rot) & 3)) {
            f32x4 acce = {0.f, 0.f, 0.f, 0.f};
            #pragma unroll
            for (int cc = 0; cc < 4; ++cc) {
                const bf16x8 bhe = *(const bf16x8*)(WThiE + cc * 32);
                const bf16x8 ble = *(const bf16x8*)(WTloE + cc * 32);
                acce = __builtin_amdgcn_mfma_f32_16x16x32_bf16(ah[cc], bhe, acce, 0, 0, 0);
                acce = __builtin_amdgcn_mfma_f32_16x16x32_bf16(ah[cc], ble, acce, 0, 0, 0);
            }
            if (r16 == 0) {
                #pragma unroll
                for (int r = 0; r < 4; ++r) asrcN[rowb + r] = acce[r];
            } else if (r16 == 1) {
                #pragma unroll
                for (int r = 0; r < 4; ++r) adstN[rowb + r] = acce[r];
            }
        }

        __syncthreads();
        cur ^= 1;
    }
}

// ---------------- CSR build: 196-bucket two-level scatter ----------------
__global__ __launch_bounds__(256) void bucket_scan(const int* __restrict__ bcnt_part,
                                                   int* __restrict__ bbase,
                                                   int* __restrict__ bcur,
                                                   int* __restrict__ off) {
    __shared__ int s[256];
    const int tid = threadIdx.x;
    int sum = 0;
    for (int p = 0; p < BIN_BLOCKS; ++p) sum += bcnt_part[p * BWIDTH + tid];
    s[tid] = (tid < NBUCK) ? sum : 0;
    __syncthreads();
    #pragma unroll
    for (int d = 1; d < 256; d <<= 1) {
        int t = (tid >= d) ? s[tid - d] : 0;
        __syncthreads();
        s[tid] += t;
        __syncthreads();
    }
    if (tid < NBUCK) {
        const int base = (tid == 0) ? 0 : s[tid - 1];
        bbase[tid] = base;
        bcur[tid] = base;
    }
    if (tid == 0) { bbase[NBUCK] = EN_TOTAL; off[N_NODES] = EN_TOTAL; }
}

__global__ __launch_bounds__(256) void bin_edges(const int* __restrict__ ei,
                                                 const int* __restrict__ bcnt_part,
                                                 int* __restrict__ bcur,
                                                 unsigned int* __restrict__ ebuf) {
    __shared__ int hist[NBUCK], base[NBUCK];
    const int tid = threadIdx.x;
    if (tid < NBUCK) {
        const int h = bcnt_part[blockIdx.x * BWIDTH + tid];
        base[tid] = h ? atomicAdd(&bcur[tid], h) : 0;
        hist[tid] = 0;
    }
    __syncthreads();
    const int i0 = blockIdx.x * BIN_BATCH;
    const int i1 = min(i0 + BIN_BATCH, EN_TOTAL);
    for (int i = i0 + tid; i < i1; i += 256) {
        int s, d;
        if (i < N_EDGES) { s = ei[i]; d = ei[N_EDGES + i]; }
        else             { s = d = i - N_EDGES; }
        const int b = d >> BSHIFT;
        const int r = atomicAdd(&hist[b], 1);
        ebuf[base[b] + r] = ((unsigned int)(d & (BWIDTH - 1)) << 17) | (unsigned int)s;
    }
}

__global__ __launch_bounds__(512) void place_edges(
    const int* __restrict__ bbase, const unsigned int* __restrict__ ebuf,
    int* __restrict__ off, int* __restrict__ srcs)
{
    __shared__ int hist[BWIDTH], scn[BWIDTH];
    const int b = blockIdx.x, tid = threadIdx.x;
    const int d0 = b << BSHIFT;
    const int nd = min(BWIDTH, N_NODES - d0);
    const int bstart = bbase[b], bend = bbase[b + 1];

    if (tid < BWIDTH) hist[tid] = 0;
    __syncthreads();
    for (int i = bstart + tid; i < bend; i += 512)
        atomicAdd(&hist[ebuf[i] >> 17], 1);
    __syncthreads();
    if (tid < BWIDTH) scn[tid] = hist[tid];
    __syncthreads();
    #pragma unroll
    for (int d = 1; d < BWIDTH; d <<= 1) {
        int t = (tid < BWIDTH && tid >= d) ? scn[tid - d] : 0;
        __syncthreads();
        if (tid < BWIDTH) scn[tid] += t;
        __syncthreads();
    }
    if (tid < nd) {
        const int start = bstart + (tid ? scn[tid - 1] : 0);
        off[d0 + tid] = start;
        hist[tid] = start;          // reuse as scatter cursor
    }
    __syncthreads();
    for (int i = bstart + tid; i < bend; i += 512) {
        const unsigned int e = ebuf[i];
        const int p = atomicAdd(&hist[e >> 17], 1);
        srcs[p] = (int)(e & 0x1FFFFu);
    }
}

// ---------------- segment softmax + weighted aggregation ----------------
// mode 0: relu + bf16 write to PHI (next layer's single-plane gemm input)
// mode 1: no relu + fp32 write (pool input)
__global__ __launch_bounds__(256) void gat_aggregate(
    const unsigned short* __restrict__ Hb, const int* __restrict__ off,
    const int* __restrict__ srcs,
    const float* __restrict__ asrcN, const float* __restrict__ adstN,
    const float* __restrict__ bias,
    unsigned short* __restrict__ PHI, float* __restrict__ OUTF, int mode)
{
    const int wave = threadIdx.x >> 6, lane = threadIdx.x & 63;
    const int grp = lane >> 3, fl = lane & 7;

    for (int n = blockIdx.x * 4 + wave; n < N_NODES; n += gridDim.x * 4) {
        const int s0 = off[n], s1 = off[n + 1];
        const int deg = s1 - s0;
        const float ad = adstN[n];

        float e_reg = -1e30f;
        float m = -1e30f;
        for (int j = s0 + lane; j < s1; j += 64) {
            float e = lrelu(asrcN[srcs[j]] + ad);
            if (j - s0 < 64) e_reg = e;
            m = fmaxf(m, e);
        }
        #pragma unroll
        for (int o = 32; o; o >>= 1) m = fmaxf(m, __shfl_xor(m, o));
        const float ex_reg = (lane < deg) ? __expf(e_reg - m) : 0.f;

        float4 a0 = {0,0,0,0}, a1 = {0,0,0,0}, a2 = {0,0,0,0}, a3 = {0,0,0,0};
        float dn = 0.f;
        const unsigned short* Hf = Hb + (size_t)fl * 16;
        for (int j = s0 + grp; j < s1; j += 8) {
            const int s = srcs[j];
            const float ex = (deg <= 64)
                ? __shfl(ex_reg, j - s0)
                : __expf(lrelu(asrcN[s] + ad) - m);
            dn += ex;
            const uint4* hp = (const uint4*)(Hf + (size_t)s * FDIM);
            const uint4 u0 = hp[0], u1 = hp[1];
            a0.x += ex * __uint_as_float(u0.x << 16);
            a0.y += ex * __uint_as_float(u0.x & 0xffff0000u);
            a0.z += ex * __uint_as_float(u0.y << 16);
            a0.w += ex * __uint_as_float(u0.y & 0xffff0000u);
            a1.x += ex * __uint_as_float(u0.z << 16);
            a1.y += ex * __uint_as_float(u0.z & 0xffff0000u);
            a1.z += ex * __uint_as_float(u0.w << 16);
            a1.w += ex * __uint_as_float(u0.w & 0xffff0000u);
            a2.x += ex * __uint_as_float(u1.x << 16);
            a2.y += ex * __uint_as_float(u1.x & 0xffff0000u);
            a2.z += ex * __uint_as_float(u1.y << 16);
            a2.w += ex * __uint_as_float(u1.y & 0xffff0000u);
            a3.x += ex * __uint_as_float(u1.z << 16);
            a3.y += ex * __uint_as_float(u1.z & 0xffff0000u);
            a3.z += ex * __uint_as_float(u1.w << 16);
            a3.w += ex * __uint_as_float(u1.w & 0xffff0000u);
        }

        #pragma unroll
        for (int o = 8; o <= 32; o <<= 1) {
            dn  += __shfl_xor(dn, o);
            a0.x += __shfl_xor(a0.x, o); a0.y += __shfl_xor(a0.y, o);
            a0.z += __shfl_xor(a0.z, o); a0.w += __shfl_xor(a0.w, o);
            a1.x += __shfl_xor(a1.x, o); a1.y += __shfl_xor(a1.y, o);
            a1.z += __shfl_xor(a1.z, o); a1.w += __shfl_xor(a1.w, o);
            a2.x += __shfl_xor(a2.x, o); a2.y += __shfl_xor(a2.y, o);
            a2.z += __shfl_xor(a2.z, o); a2.w += __shfl_xor(a2.w, o);
            a3.x += __shfl_xor(a3.x, o); a3.y += __shfl_xor(a3.y, o);
            a3.z += __shfl_xor(a3.z, o); a3.w += __shfl_xor(a3.w, o);
        }

        if (grp == 0) {
            const float rd = 1.f / dn;
            const float4* bp = (const float4*)(bias + fl * 16);
            float4 ov[4] = {a0, a1, a2, a3};
            #pragma unroll
            for (int q = 0; q < 4; ++q) {
                const float4 b4 = bp[q];
                float4 o4;
                o4.x = ov[q].x * rd + b4.x; o4.y = ov[q].y * rd + b4.y;
                o4.z = ov[q].z * rd + b4.z; o4.w = ov[q].w * rd + b4.w;
                if (mode == 0) {
                    o4.x = fmaxf(o4.x, 0.f); o4.y = fmaxf(o4.y, 0.f);
                    o4.z = fmaxf(o4.z, 0.f); o4.w = fmaxf(o4.w, 0.f);
                    ushort4 h4;
                    h4.x = f2bf(o4.x);
                    h4.y = f2bf(o4.y);
                    h4.z = f2bf(o4.z);
                    h4.w = f2bf(o4.w);
                    *(ushort4*)(PHI + (size_t)n * FDIM + fl * 16 + q * 4) = h4;
                } else {
                    *(float4*)(OUTF + (size_t)n * FDIM + fl * 16 + q * 4) = o4;
                }
            }
        }
    }
}

// ---------------- global mean pool + final linear (8 rows in flight) ----------
__global__ __launch_bounds__(256) void pool_linear2(
    const float* __restrict__ H, const int* __restrict__ batch,
    const float* __restrict__ Wlin, const float* __restrict__ blin,
    float* __restrict__ out)
{
    const int g = blockIdx.x, tid = threadIdx.x;
    const int rl = tid >> 5, fq = tid & 31;

    int a = 0, b = N_NODES;
    while (a < b) { int mid = (a + b) >> 1; if (batch[mid] < g) a = mid + 1; else b = mid; }
    const int lo = a;
    b = N_NODES;
    while (a < b) { int mid = (a + b) >> 1; if (batch[mid] <= g) a = mid + 1; else b = mid; }
    const int hi = a;

    float4 acc = {0.f, 0.f, 0.f, 0.f};
    for (int n = lo + rl; n < hi; n += 8) {
        const float4 v = *(const float4*)(H + (size_t)n * FDIM + fq * 4);
        acc.x += v.x; acc.y += v.y; acc.z += v.z; acc.w += v.w;
    }
    __shared__ float4 s[8][32];
    s[rl][fq] = acc;
    __syncthreads();

    if (tid < 32) {
        float4 t = s[0][fq];
        #pragma unroll
        for (int r = 1; r < 8; ++r) {
            const float4 v = s[r][fq];
            t.x += v.x; t.y += v.y; t.z += v.z; t.w += v.w;
        }
        const float inv = 1.f / fmaxf((float)(hi - lo), 1.f);
        t.x *= inv; t.y *= inv; t.z *= inv; t.w *= inv;
        float d0 = t.x * Wlin[(fq * 4 + 0) * 2 + 0] + t.y * Wlin[(fq * 4 + 1) * 2 + 0]
                 + t.z * Wlin[(fq * 4 + 2) * 2 + 0] + t.w * Wlin[(fq * 4 + 3) * 2 + 0];
        float d1 = t.x * Wlin[(fq * 4 + 0) * 2 + 1] + t.y * Wlin[(fq * 4 + 1) * 2 + 1]
                 + t.z * Wlin[(fq * 4 + 2) * 2 + 1] + t.w * Wlin[(fq * 4 + 3) * 2 + 1];
        #pragma unroll
        for (int o = 1; o <= 16; o <<= 1) {
            d0 += __shfl_xor(d0, o);
            d1 += __shfl_xor(d1, o);
        }
        if (fq == 0) {
            out[g * 2 + 0] = d0 + blin[0];
            out[g * 2 + 1] = d1 + blin[1];
        }
    }
}

extern "C" void kernel_launch(void* const* d_in, const int* in_sizes, int n_in,
                              void* d_out, int out_size, void* d_ws, size_t ws_size,
                              hipStream_t stream)
{
    const float* x     = (const float*)d_in[0];
    const int*   ei    = (const int*)d_in[1];
    const int*   batch = (const int*)d_in[2];
    const float* W[3]    = {(const float*)d_in[3],  (const float*)d_in[7],  (const float*)d_in[11]};
    const float* avs[3]  = {(const float*)d_in[4],  (const float*)d_in[8],  (const float*)d_in[12]};
    const float* avd[3]  = {(const float*)d_in[5],  (const float*)d_in[9],  (const float*)d_in[13]};
    const float* bias[3] = {(const float*)d_in[6],  (const float*)d_in[10], (const float*)d_in[14]};
    const float* Wlin = (const float*)d_in[15];
    const float* blin = (const float*)d_in[16];
    float* out = (float*)d_out;

    char* w = (char*)d_ws;
    unsigned short* PHI = (unsigned short*)w; w += (size_t)N_NODES * FDIM * 4;  // 12.8MB used + 12.8MB pad (hOf span)
    float* hOf = (float*)PHI;                                                   // 25.6 MB overlay (pool input)
    unsigned short* Hb = (unsigned short*)w; w += (size_t)N_NODES * FDIM * 2;   // 12.8 MB
    float* attn  = (float*)w; w += 2 * 200192;
    int*   off   = (int*)w;   w += 200192;
    int*   bcnt_part = (int*)w; w += (size_t)BIN_BLOCKS * BWIDTH * 4;           // 104 KB
    int*   bbase = (int*)w;   w += 1024;
    int*   bcur  = (int*)w;   w += 1024;
    int*   srcs  = (int*)w;   w += (size_t)EN_TOTAL * 4;
    unsigned int* ebuf = (unsigned int*)w; w += (size_t)EN_TOTAL * 4;           // 3.4 MB
    unsigned short* WT = (unsigned short*)w; w += (size_t)3 * 2 * WT_COLS * FDIM * 2;  // 221 KB
    float* asrcN = attn;
    float* adstN = attn + N_NODES;

    // ---- fused prep (WT + bf16 X plane + per-block bucket histograms) ----
    prep_all<<<PREP_GRID, 256, 0, stream>>>(x, ei, W[0], W[1], W[2],
                                            avs[0], avs[1], avs[2],
                                            avd[0], avd[1], avd[2],
                                            WT, PHI, bcnt_part);

    // ---- CSR by destination: 196-bucket two-level scatter ----
    bucket_scan<<<1, 256, 0, stream>>>(bcnt_part, bbase, bcur, off);
    bin_edges<<<BIN_BLOCKS, 256, 0, stream>>>(ei, bcnt_part, bcur, ebuf);
    place_edges<<<NBUCK, 512, 0, stream>>>(bbase, ebuf, off, srcs);

    // ---- 3 GAT layers ----
    for (int l = 0; l < 3; ++l) {
        const unsigned short* WThi = WT + (size_t)l * 2 * WT_COLS * FDIM;
        const unsigned short* WTlo = WThi + WT_COLS * FDIM;
        gemm_mfma10<<<1024, 256, 0, stream>>>(PHI, WThi, WTlo, Hb, asrcN, adstN);
        gat_aggregate<<<2048, 256, 0, stream>>>(Hb, off, srcs, asrcN, adstN, bias[l],
                                                PHI, hOf, (l < 2) ? 0 : 1);
    }

    // ---- mean pool + linear ----
    pool_linear2<<<N_GRAPHS, 256, 0, stream>>>(hOf, batch, Wlin, blin, out);
}

// Round 20
// 287.698 us; speedup vs baseline: 1.0993x; 1.0993x over previous
//
#include <hip/hip_runtime.h>
#include <math.h>

#define N_NODES  50000
#define N_EDGES  800000
#define FDIM     128
#define N_GRAPHS 500
#define NEG_SLOPE 0.2f
#define EN_TOTAL (N_EDGES + N_NODES)
#define GEMM_TILES (N_NODES / 16)         // 3125 exact
#define WT_COLS 144                        // 128 + [wa_src, wa_dst, 14 zero]
#define PREP_PLANE_BLOCKS 1024
#define BSHIFT 8
#define BWIDTH 256
#define NBUCK ((N_NODES + BWIDTH - 1) / BWIDTH)   // 196
#define BIN_BATCH 8192
#define BIN_BLOCKS ((EN_TOTAL + BIN_BATCH - 1) / BIN_BATCH)  // 104
#define PREP_GRID (3 + PREP_PLANE_BLOCKS + BIN_BLOCKS)

typedef short bf16x8 __attribute__((ext_vector_type(8)));
typedef float f32x4 __attribute__((ext_vector_type(4)));
typedef const __attribute__((address_space(1))) void* gas_ptr;
typedef __attribute__((address_space(3))) void* las_ptr;

static __device__ __forceinline__ float lrelu(float x) {
    return x >= 0.f ? x : NEG_SLOPE * x;
}
static __device__ __forceinline__ unsigned short f2bf(float v) {
    unsigned int u = __float_as_uint(v);
    u += 0x7fffu + ((u >> 16) & 1u);
    return (unsigned short)(u >> 16);
}
static __device__ __forceinline__ float bf2f(unsigned short s) {
    return __uint_as_float(((unsigned int)s) << 16);
}

// ---- fused prep: blocks 0-2 build WT; blocks 3..1026 split X (hi/lo);
//      blocks 1027..1130 write per-block bucket histograms (no atomics).
__global__ __launch_bounds__(256) void prep_all(
    const float* __restrict__ X, const int* __restrict__ ei,
    const float* __restrict__ W0, const float* __restrict__ W1,
    const float* __restrict__ W2,
    const float* __restrict__ as0, const float* __restrict__ as1,
    const float* __restrict__ as2,
    const float* __restrict__ ad0, const float* __restrict__ ad1,
    const float* __restrict__ ad2,
    unsigned short* __restrict__ WT,
    unsigned short* __restrict__ PHI, unsigned short* __restrict__ PLO,
    int* __restrict__ bcnt_part)
{
    __shared__ float wa[256];
    __shared__ int hist[BWIDTH];
    const int b = blockIdx.x, tid = threadIdx.x;

    if (b < 3) {
        const float* W  = (b == 0) ? W0  : (b == 1) ? W1  : W2;
        const float* As = (b == 0) ? as0 : (b == 1) ? as1 : as2;
        const float* Ad = (b == 0) ? ad0 : (b == 1) ? ad1 : ad2;
        unsigned short* hi = WT + (size_t)b * 2 * WT_COLS * FDIM;
        unsigned short* lo = hi + WT_COLS * FDIM;
        {
            const int k = tid & 127;
            const float* av = (tid < 128) ? As : Ad;
            float s = 0.f;
            for (int c = 0; c < 128; ++c) s += W[k * FDIM + c] * av[c];
            wa[tid] = s;
        }
        __syncthreads();
        for (int i = tid; i < FDIM * FDIM; i += 256) {
            const int k = i >> 7, c = i & 127;
            const float v = W[i];
            const unsigned short h = f2bf(v);
            hi[c * FDIM + k] = h;
            lo[c * FDIM + k] = f2bf(v - bf2f(h));
        }
        for (int k = tid; k < FDIM; k += 256) {
            const float vs = wa[k], vd = wa[128 + k];
            const unsigned short hs = f2bf(vs), hd = f2bf(vd);
            hi[128 * FDIM + k] = hs; lo[128 * FDIM + k] = f2bf(vs - bf2f(hs));
            hi[129 * FDIM + k] = hd; lo[129 * FDIM + k] = f2bf(vd - bf2f(hd));
        }
        for (int i = tid; i < 14 * FDIM; i += 256) {
            hi[130 * FDIM + i] = 0;
            lo[130 * FDIM + i] = 0;
        }
    } else if (b < 3 + PREP_PLANE_BLOCKS) {
        const int total = N_NODES * FDIM / 4;
        for (int i = (b - 3) * 256 + tid; i < total; i += PREP_PLANE_BLOCKS * 256) {
            const float4 v = ((const float4*)X)[i];
            ushort4 h4, l4;
            h4.x = f2bf(v.x); l4.x = f2bf(v.x - bf2f(h4.x));
            h4.y = f2bf(v.y); l4.y = f2bf(v.y - bf2f(h4.y));
            h4.z = f2bf(v.z); l4.z = f2bf(v.z - bf2f(h4.z));
            h4.w = f2bf(v.w); l4.w = f2bf(v.w - bf2f(h4.w));
            ((ushort4*)PHI)[i] = h4;
            ((ushort4*)PLO)[i] = l4;
        }
    } else {
        const int cb = b - 3 - PREP_PLANE_BLOCKS;       // 0..BIN_BLOCKS-1
        if (tid < BWIDTH) hist[tid] = 0;
        __syncthreads();
        const int i0 = cb * BIN_BATCH;
        const int i1 = min(i0 + BIN_BATCH, EN_TOTAL);
        for (int i = i0 + tid; i < i1; i += 256) {
            const int d = (i < N_EDGES) ? ei[N_EDGES + i] : (i - N_EDGES);
            atomicAdd(&hist[d >> BSHIFT], 1);
        }
        __syncthreads();
        if (tid < BWIDTH) bcnt_part[cb * BWIDTH + tid] = hist[tid];
    }
}

// ---------------- h = X @ W, persistent-B MFMA, global_load_lds staging -------
// Grid 782: every block owns exactly 4 tiles (B frags amortized 4x, no tail).
// Staging: LINEAR LDS dest via global_load_lds w=16; XOR slot swizzle applied
// to the per-lane GLOBAL source (rule #21, XOR involution) so the swizzled
// ds_read pattern in the compute is unchanged. Next tile's loads issued before
// this tile's MFMAs; __syncthreads drains them.
__global__ __launch_bounds__(256) void gemm_mfma9(
    const unsigned short* __restrict__ PHI, const unsigned short* __restrict__ PLO,
    const unsigned short* __restrict__ WThi, const unsigned short* __restrict__ WTlo,
    unsigned short* __restrict__ Hb, float* __restrict__ asrcN, float* __restrict__ adstN)
{
    __shared__ unsigned short sH[2][16 * 128];
    __shared__ unsigned short sL[2][16 * 128];

    const int tid = threadIdx.x, wv = tid >> 6, lane = tid & 63;
    const int r16 = lane & 15, g = lane >> 4;
    const int t0 = wv * 2;

    bf16x8 bh[2][4], bl[2][4];
    #pragma unroll
    for (int tt = 0; tt < 2; ++tt) {
        const int c = (t0 + tt) * 16 + r16;
        #pragma unroll
        for (int cc = 0; cc < 4; ++cc) {
            bh[tt][cc] = *(const bf16x8*)(WThi + c * FDIM + cc * 32 + 8 * g);
            bl[tt][cc] = *(const bf16x8*)(WTlo + c * FDIM + cc * 32 + 8 * g);
        }
    }
    const unsigned short* WThiE = WThi + (128 + r16) * FDIM + 8 * g;
    const unsigned short* WTloE = WTlo + (128 + r16) * FDIM + 8 * g;

    // staging geometry: per-lane swizzled GLOBAL source; linear LDS dest
    const int srow = wv * 4 + (lane >> 4);
    const int gslot = (lane & 15) ^ (srow & 7);              // XOR involution
    const size_t gOfs0 = (size_t)srow * FDIM + gslot * 8;    // ushort units

    int tile = blockIdx.x;
    {
        const size_t go = (size_t)tile * 16 * FDIM + gOfs0;
        __builtin_amdgcn_global_load_lds((gas_ptr)(PHI + go), (las_ptr)&sH[0][wv * 512], 16, 0, 0);
        __builtin_amdgcn_global_load_lds((gas_ptr)(PLO + go), (las_ptr)&sL[0][wv * 512], 16, 0, 0);
    }
    __syncthreads();

    int cur = 0, rot = 0;
    for (; tile < GEMM_TILES; tile += gridDim.x, ++rot) {
        const int nxt = tile + (int)gridDim.x;
        if (nxt < GEMM_TILES) {
            const size_t go = (size_t)nxt * 16 * FDIM + gOfs0;
            __builtin_amdgcn_global_load_lds((gas_ptr)(PHI + go),
                                             (las_ptr)&sH[cur ^ 1][wv * 512], 16, 0, 0);
            __builtin_amdgcn_global_load_lds((gas_ptr)(PLO + go),
                                             (las_ptr)&sL[cur ^ 1][wv * 512], 16, 0, 0);
        }

        bf16x8 ah[4], al[4];
        #pragma unroll
        for (int cc = 0; cc < 4; ++cc) {
            const int p = (cc * 4 + g) ^ (r16 & 7);
            const int ofs = r16 * 128 + p * 8;
            ah[cc] = *(const bf16x8*)(&sH[cur][ofs]);
            al[cc] = *(const bf16x8*)(&sL[cur][ofs]);
        }

        f32x4 acc0 = {0.f, 0.f, 0.f, 0.f}, acc1 = {0.f, 0.f, 0.f, 0.f};
        #pragma unroll
        for (int cc = 0; cc < 4; ++cc) {
            acc0 = __builtin_amdgcn_mfma_f32_16x16x32_bf16(ah[cc], bh[0][cc], acc0, 0, 0, 0);
            acc1 = __builtin_amdgcn_mfma_f32_16x16x32_bf16(ah[cc], bh[1][cc], acc1, 0, 0, 0);
            acc0 = __builtin_amdgcn_mfma_f32_16x16x32_bf16(al[cc], bh[0][cc], acc0, 0, 0, 0);
            acc1 = __builtin_amdgcn_mfma_f32_16x16x32_bf16(al[cc], bh[1][cc], acc1, 0, 0, 0);
            acc0 = __builtin_amdgcn_mfma_f32_16x16x32_bf16(ah[cc], bl[0][cc], acc0, 0, 0, 0);
            acc1 = __builtin_amdgcn_mfma_f32_16x16x32_bf16(ah[cc], bl[1][cc], acc1, 0, 0, 0);
        }

        const int m0 = tile * 16;
        const int rowb = m0 + 4 * g;
        #pragma unroll
        for (int r = 0; r < 4; ++r) {
            Hb[(size_t)(rowb + r) * FDIM + (t0 + 0) * 16 + r16] = f2bf(acc0[r]);
            Hb[(size_t)(rowb + r) * FDIM + (t0 + 1) * 16 + r16] = f2bf(acc1[r]);
        }

        if (wv == ((tile + rot) & 3)) {
            f32x4 acce = {0.f, 0.f, 0.f, 0.f};
            #pragma unroll
            for (int cc = 0; cc < 4; ++cc) {
                const bf16x8 bhe = *(const bf16x8*)(WThiE + cc * 32);
                const bf16x8 ble = *(const bf16x8*)(WTloE + cc * 32);
                acce = __builtin_amdgcn_mfma_f32_16x16x32_bf16(ah[cc], bhe, acce, 0, 0, 0);
                acce = __builtin_amdgcn_mfma_f32_16x16x32_bf16(al[cc], bhe, acce, 0, 0, 0);
                acce = __builtin_amdgcn_mfma_f32_16x16x32_bf16(ah[cc], ble, acce, 0, 0, 0);
            }
            if (r16 == 0) {
                #pragma unroll
                for (int r = 0; r < 4; ++r) asrcN[rowb + r] = acce[r];
            } else if (r16 == 1) {
                #pragma unroll
                for (int r = 0; r < 4; ++r) adstN[rowb + r] = acce[r];
            }
        }

        __syncthreads();
        cur ^= 1;
    }
}

// ---------------- CSR build: 196-bucket two-level scatter ----------------
__global__ __launch_bounds__(256) void bucket_scan(const int* __restrict__ bcnt_part,
                                                   int* __restrict__ bbase,
                                                   int* __restrict__ bcur,
                                                   int* __restrict__ off) {
    __shared__ int s[256];
    const int tid = threadIdx.x;
    int sum = 0;
    for (int p = 0; p < BIN_BLOCKS; ++p) sum += bcnt_part[p * BWIDTH + tid];
    s[tid] = (tid < NBUCK) ? sum : 0;
    __syncthreads();
    #pragma unroll
    for (int d = 1; d < 256; d <<= 1) {
        int t = (tid >= d) ? s[tid - d] : 0;
        __syncthreads();
        s[tid] += t;
        __syncthreads();
    }
    if (tid < NBUCK) {
        const int base = (tid == 0) ? 0 : s[tid - 1];
        bbase[tid] = base;
        bcur[tid] = base;
    }
    if (tid == 0) { bbase[NBUCK] = EN_TOTAL; off[N_NODES] = EN_TOTAL; }
}

// uses the saved per-block histogram (no counting pass)
__global__ __launch_bounds__(256) void bin_edges(const int* __restrict__ ei,
                                                 const int* __restrict__ bcnt_part,
                                                 int* __restrict__ bcur,
                                                 unsigned int* __restrict__ ebuf) {
    __shared__ int hist[NBUCK], base[NBUCK];
    const int tid = threadIdx.x;
    if (tid < NBUCK) {
        const int h = bcnt_part[blockIdx.x * BWIDTH + tid];
        base[tid] = h ? atomicAdd(&bcur[tid], h) : 0;
        hist[tid] = 0;
    }
    __syncthreads();
    const int i0 = blockIdx.x * BIN_BATCH;
    const int i1 = min(i0 + BIN_BATCH, EN_TOTAL);
    for (int i = i0 + tid; i < i1; i += 256) {
        int s, d;
        if (i < N_EDGES) { s = ei[i]; d = ei[N_EDGES + i]; }
        else             { s = d = i - N_EDGES; }
        const int b = d >> BSHIFT;
        const int r = atomicAdd(&hist[b], 1);
        ebuf[base[b] + r] = ((unsigned int)(d & (BWIDTH - 1)) << 17) | (unsigned int)s;
    }
}

// per-bucket: LDS per-dst histogram -> local scan -> write off + scatter srcs
__global__ __launch_bounds__(512) void place_edges(
    const int* __restrict__ bbase, const unsigned int* __restrict__ ebuf,
    int* __restrict__ off, int* __restrict__ srcs)
{
    __shared__ int hist[BWIDTH], scn[BWIDTH];
    const int b = blockIdx.x, tid = threadIdx.x;
    const int d0 = b << BSHIFT;
    const int nd = min(BWIDTH, N_NODES - d0);
    const int bstart = bbase[b], bend = bbase[b + 1];

    if (tid < BWIDTH) hist[tid] = 0;
    __syncthreads();
    for (int i = bstart + tid; i < bend; i += 512)
        atomicAdd(&hist[ebuf[i] >> 17], 1);
    __syncthreads();
    if (tid < BWIDTH) scn[tid] = hist[tid];
    __syncthreads();
    #pragma unroll
    for (int d = 1; d < BWIDTH; d <<= 1) {
        int t = (tid < BWIDTH && tid >= d) ? scn[tid - d] : 0;
        __syncthreads();
        if (tid < BWIDTH) scn[tid] += t;
        __syncthreads();
    }
    if (tid < nd) {
        const int start = bstart + (tid ? scn[tid - 1] : 0);
        off[d0 + tid] = start;
        hist[tid] = start;          // reuse as scatter cursor
    }
    __syncthreads();
    for (int i = bstart + tid; i < bend; i += 512) {
        const unsigned int e = ebuf[i];
        const int p = atomicAdd(&hist[e >> 17], 1);
        srcs[p] = (int)(e & 0x1FFFFu);
    }
}

// ---------------- segment softmax + weighted aggregation (R18-exact) ----------
__global__ __launch_bounds__(256) void gat_aggregate(
    const unsigned short* __restrict__ Hb, const int* __restrict__ off,
    const int* __restrict__ srcs,
    const float* __restrict__ asrcN, const float* __restrict__ adstN,
    const float* __restrict__ bias,
    unsigned short* __restrict__ PHI, unsigned short* __restrict__ PLO,
    float* __restrict__ OUTF, int mode)
{
    const int wave = threadIdx.x >> 6, lane = threadIdx.x & 63;
    const int grp = lane >> 3, fl = lane & 7;

    for (int n = blockIdx.x * 4 + wave; n < N_NODES; n += gridDim.x * 4) {
        const int s0 = off[n], s1 = off[n + 1];
        const int deg = s1 - s0;
        const float ad = adstN[n];

        float e_reg = -1e30f;
        float m = -1e30f;
        for (int j = s0 + lane; j < s1; j += 64) {
            float e = lrelu(asrcN[srcs[j]] + ad);
            if (j - s0 < 64) e_reg = e;
            m = fmaxf(m, e);
        }
        #pragma unroll
        for (int o = 32; o; o >>= 1) m = fmaxf(m, __shfl_xor(m, o));
        const float ex_reg = (lane < deg) ? __expf(e_reg - m) : 0.f;

        float4 a0 = {0,0,0,0}, a1 = {0,0,0,0}, a2 = {0,0,0,0}, a3 = {0,0,0,0};
        float dn = 0.f;
        const unsigned short* Hf = Hb + (size_t)fl * 16;
        for (int j = s0 + grp; j < s1; j += 8) {
            const int s = srcs[j];
            const float ex = (deg <= 64)
                ? __shfl(ex_reg, j - s0)
                : __expf(lrelu(asrcN[s] + ad) - m);
            dn += ex;
            const uint4* hp = (const uint4*)(Hf + (size_t)s * FDIM);
            const uint4 u0 = hp[0], u1 = hp[1];
            a0.x += ex * __uint_as_float(u0.x << 16);
            a0.y += ex * __uint_as_float(u0.x & 0xffff0000u);
            a0.z += ex * __uint_as_float(u0.y << 16);
            a0.w += ex * __uint_as_float(u0.y & 0xffff0000u);
            a1.x += ex * __uint_as_float(u0.z << 16);
            a1.y += ex * __uint_as_float(u0.z & 0xffff0000u);
            a1.z += ex * __uint_as_float(u0.w << 16);
            a1.w += ex * __uint_as_float(u0.w & 0xffff0000u);
            a2.x += ex * __uint_as_float(u1.x << 16);
            a2.y += ex * __uint_as_float(u1.x & 0xffff0000u);
            a2.z += ex * __uint_as_float(u1.y << 16);
            a2.w += ex * __uint_as_float(u1.y & 0xffff0000u);
            a3.x += ex * __uint_as_float(u1.z << 16);
            a3.y += ex * __uint_as_float(u1.z & 0xffff0000u);
            a3.z += ex * __uint_as_float(u1.w << 16);
            a3.w += ex * __uint_as_float(u1.w & 0xffff0000u);
        }

        #pragma unroll
        for (int o = 8; o <= 32; o <<= 1) {
            dn  += __shfl_xor(dn, o);
            a0.x += __shfl_xor(a0.x, o); a0.y += __shfl_xor(a0.y, o);
            a0.z += __shfl_xor(a0.z, o); a0.w += __shfl_xor(a0.w, o);
            a1.x += __shfl_xor(a1.x, o); a1.y += __shfl_xor(a1.y, o);
            a1.z += __shfl_xor(a1.z, o); a1.w += __shfl_xor(a1.w, o);
            a2.x += __shfl_xor(a2.x, o); a2.y += __shfl_xor(a2.y, o);
            a2.z += __shfl_xor(a2.z, o); a2.w += __shfl_xor(a2.w, o);
            a3.x += __shfl_xor(a3.x, o); a3.y += __shfl_xor(a3.y, o);
            a3.z += __shfl_xor(a3.z, o); a3.w += __shfl_xor(a3.w, o);
        }

        if (grp == 0) {
            const float rd = 1.f / dn;
            const float4* bp = (const float4*)(bias + fl * 16);
            float4 ov[4] = {a0, a1, a2, a3};
            #pragma unroll
            for (int q = 0; q < 4; ++q) {
                const float4 b4 = bp[q];
                float4 o4;
                o4.x = ov[q].x * rd + b4.x; o4.y = ov[q].y * rd + b4.y;
                o4.z = ov[q].z * rd + b4.z; o4.w = ov[q].w * rd + b4.w;
                if (mode == 0) {
                    o4.x = fmaxf(o4.x, 0.f); o4.y = fmaxf(o4.y, 0.f);
                    o4.z = fmaxf(o4.z, 0.f); o4.w = fmaxf(o4.w, 0.f);
                    ushort4 h4, l4;
                    h4.x = f2bf(o4.x); l4.x = f2bf(o4.x - bf2f(h4.x));
                    h4.y = f2bf(o4.y); l4.y = f2bf(o4.y - bf2f(h4.y));
                    h4.z = f2bf(o4.z); l4.z = f2bf(o4.z - bf2f(h4.z));
                    h4.w = f2bf(o4.w); l4.w = f2bf(o4.w - bf2f(h4.w));
                    const size_t base = (size_t)n * FDIM + fl * 16 + q * 4;
                    *(ushort4*)(PHI + base) = h4;
                    *(ushort4*)(PLO + base) = l4;
                } else {
                    *(float4*)(OUTF + (size_t)n * FDIM + fl * 16 + q * 4) = o4;
                }
            }
        }
    }
}

// ---------------- global mean pool + final linear (8 rows in flight) ----------
__global__ __launch_bounds__(256) void pool_linear2(
    const float* __restrict__ H, const int* __restrict__ batch,
    const float* __restrict__ Wlin, const float* __restrict__ blin,
    float* __restrict__ out)
{
    const int g = blockIdx.x, tid = threadIdx.x;
    const int rl = tid >> 5, fq = tid & 31;

    int a = 0, b = N_NODES;
    while (a < b) { int mid = (a + b) >> 1; if (batch[mid] < g) a = mid + 1; else b = mid; }
    const int lo = a;
    b = N_NODES;
    while (a < b) { int mid = (a + b) >> 1; if (batch[mid] <= g) a = mid + 1; else b = mid; }
    const int hi = a;

    float4 acc = {0.f, 0.f, 0.f, 0.f};
    for (int n = lo + rl; n < hi; n += 8) {
        const float4 v = *(const float4*)(H + (size_t)n * FDIM + fq * 4);
        acc.x += v.x; acc.y += v.y; acc.z += v.z; acc.w += v.w;
    }
    __shared__ float4 s[8][32];
    s[rl][fq] = acc;
    __syncthreads();

    if (tid < 32) {
        float4 t = s[0][fq];
        #pragma unroll
        for (int r = 1; r < 8; ++r) {
            const float4 v = s[r][fq];
            t.x += v.x; t.y += v.y; t.z += v.z; t.w += v.w;
        }
        const float inv = 1.f / fmaxf((float)(hi - lo), 1.f);
        t.x *= inv; t.y *= inv; t.z *= inv; t.w *= inv;
        float d0 = t.x * Wlin[(fq * 4 + 0) * 2 + 0] + t.y * Wlin[(fq * 4 + 1) * 2 + 0]
                 + t.z * Wlin[(fq * 4 + 2) * 2 + 0] + t.w * Wlin[(fq * 4 + 3) * 2 + 0];
        float d1 = t.x * Wlin[(fq * 4 + 0) * 2 + 1] + t.y * Wlin[(fq * 4 + 1) * 2 + 1]
                 + t.z * Wlin[(fq * 4 + 2) * 2 + 1] + t.w * Wlin[(fq * 4 + 3) * 2 + 1];
        #pragma unroll
        for (int o = 1; o <= 16; o <<= 1) {
            d0 += __shfl_xor(d0, o);
            d1 += __shfl_xor(d1, o);
        }
        if (fq == 0) {
            out[g * 2 + 0] = d0 + blin[0];
            out[g * 2 + 1] = d1 + blin[1];
        }
    }
}

extern "C" void kernel_launch(void* const* d_in, const int* in_sizes, int n_in,
                              void* d_out, int out_size, void* d_ws, size_t ws_size,
                              hipStream_t stream)
{
    const float* x     = (const float*)d_in[0];
    const int*   ei    = (const int*)d_in[1];
    const int*   batch = (const int*)d_in[2];
    const float* W[3]    = {(const float*)d_in[3],  (const float*)d_in[7],  (const float*)d_in[11]};
    const float* avs[3]  = {(const float*)d_in[4],  (const float*)d_in[8],  (const float*)d_in[12]};
    const float* avd[3]  = {(const float*)d_in[5],  (const float*)d_in[9],  (const float*)d_in[13]};
    const float* bias[3] = {(const float*)d_in[6],  (const float*)d_in[10], (const float*)d_in[14]};
    const float* Wlin = (const float*)d_in[15];
    const float* blin = (const float*)d_in[16];
    float* out = (float*)d_out;

    char* w = (char*)d_ws;
    unsigned short* PHI = (unsigned short*)w; w += (size_t)N_NODES * FDIM * 2;  // 12.8 MB
    unsigned short* PLO = (unsigned short*)w; w += (size_t)N_NODES * FDIM * 2;  // 12.8 MB
    float* hOf = (float*)PHI;                                                   // overlay
    unsigned short* Hb = (unsigned short*)w; w += (size_t)N_NODES * FDIM * 2;   // 12.8 MB
    float* attn  = (float*)w; w += 2 * 200192;
    int*   off   = (int*)w;   w += 200192;
    int*   bcnt_part = (int*)w; w += (size_t)BIN_BLOCKS * BWIDTH * 4;           // 104 KB
    int*   bbase = (int*)w;   w += 1024;
    int*   bcur  = (int*)w;   w += 1024;
    int*   srcs  = (int*)w;   w += (size_t)EN_TOTAL * 4;
    unsigned int* ebuf = (unsigned int*)w; w += (size_t)EN_TOTAL * 4;           // 3.4 MB
    unsigned short* WT = (unsigned short*)w; w += (size_t)3 * 2 * WT_COLS * FDIM * 2;  // 221 KB
    float* asrcN = attn;
    float* adstN = attn + N_NODES;

    // ---- fused prep (WT + planes + per-block bucket histograms) ----
    prep_all<<<PREP_GRID, 256, 0, stream>>>(x, ei, W[0], W[1], W[2],
                                            avs[0], avs[1], avs[2],
                                            avd[0], avd[1], avd[2],
                                            WT, PHI, PLO, bcnt_part);

    // ---- CSR by destination: 196-bucket two-level scatter ----
    bucket_scan<<<1, 256, 0, stream>>>(bcnt_part, bbase, bcur, off);
    bin_edges<<<BIN_BLOCKS, 256, 0, stream>>>(ei, bcnt_part, bcur, ebuf);
    place_edges<<<NBUCK, 512, 0, stream>>>(bbase, ebuf, off, srcs);

    // ---- 3 GAT layers ----
    for (int l = 0; l < 3; ++l) {
        const unsigned short* WThi = WT + (size_t)l * 2 * WT_COLS * FDIM;
        const unsigned short* WTlo = WThi + WT_COLS * FDIM;
        gemm_mfma9<<<782, 256, 0, stream>>>(PHI, PLO, WThi, WTlo, Hb, asrcN, adstN);
        gat_aggregate<<<2048, 256, 0, stream>>>(Hb, off, srcs, asrcN, adstN, bias[l],
                                                PHI, PLO, hOf, (l < 2) ? 0 : 1);
    }

    // ---- mean pool + linear ----
    pool_linear2<<<N_GRAPHS, 256, 0, stream>>>(hOf, batch, Wlin, blin, out);
}